// Round 1
// baseline (38.941 us; speedup 1.0000x reference)
//
#include <hip/hip_runtime.h>

// PositionalEmbedding: out[p][e] = (fmod(p*div[e], 2) == 0) ? sin(p*div[e]) : cos(p*div[e])
// P = 32768 positions, E = 1024 embedding dims. Output fp32, write-only ~134 MB.
// Input x (int32 [4,32768]) is shape-only; div (fp32 [1024]) is the freq table.

#define PE_E 1024
#define PE_P 32768

__global__ __launch_bounds__(256) void PositionalEmbedding_75685913690611_kernel(
    const float* __restrict__ div, float* __restrict__ out) {
    // Each thread: one row p, 4 consecutive columns, one float4 store.
    // E/4 = 256 column-groups per row -> idx = row*256 + cg.
    int idx = blockIdx.x * blockDim.x + threadIdx.x;  // 0 .. P*E/4-1
    int row = idx >> 8;        // / (E/4)
    int cg  = idx & 255;       // % (E/4)

    float p = (float)row;      // exact in fp32 (p < 2^15)
    float4 d = *reinterpret_cast<const float4*>(div + (cg << 2));

    float4 o;
    {
        float pe = p * d.x;  // fp32 product, matches jnp semantics
        o.x = (fmodf(pe, 2.0f) == 0.0f) ? sinf(pe) : cosf(pe);
    }
    {
        float pe = p * d.y;
        o.y = (fmodf(pe, 2.0f) == 0.0f) ? sinf(pe) : cosf(pe);
    }
    {
        float pe = p * d.z;
        o.z = (fmodf(pe, 2.0f) == 0.0f) ? sinf(pe) : cosf(pe);
    }
    {
        float pe = p * d.w;
        o.w = (fmodf(pe, 2.0f) == 0.0f) ? sinf(pe) : cosf(pe);
    }

    reinterpret_cast<float4*>(out)[idx] = o;
}

extern "C" void kernel_launch(void* const* d_in, const int* in_sizes, int n_in,
                              void* d_out, int out_size, void* d_ws, size_t ws_size,
                              hipStream_t stream) {
    const float* div = (const float*)d_in[1];  // d_in[0] = x (shape-only)
    float* out = (float*)d_out;                // out_size = 32768*1024

    int total4 = (PE_P * PE_E) / 4;            // 8,388,608 float4 stores
    int block = 256;
    int grid = total4 / block;                 // 32768 blocks
    PositionalEmbedding_75685913690611_kernel<<<grid, block, 0, stream>>>(div, out);
}

// Round 2
// 25.791 us; speedup vs baseline: 1.5099x; 1.5099x over previous
//
#include <hip/hip_runtime.h>

// PositionalEmbedding: out[p][e] = (fmod(p*div[e], 2) == 0) ? sin(p*div[e]) : cos(p*div[e])
// P = 32768 positions, E = 1024 embedding dims. Output fp32, write-only ~134 MB.
//
// Strategy: hardware v_sin_f32 (input in REVOLUTIONS, fract-reduced per
// cdna4_isa.md) instead of libm sinf/cosf. cos folded in via +0.25 rev.
// Parity test expanded to exact arithmetic (bit-identical to fmodf for
// pe < 2^24): m = pe - 2*trunc(pe*0.5) is exact in fp32.

#define PE_E 1024
#define PE_P 32768

__device__ __forceinline__ float sincos_sel(float pe) {
    // exact fmod(pe, 2): pe*0.5 exact (pow2 scale), trunc exact, 2*t exact,
    // subtraction exact (both multiples of ulp(pe), result < 2).
    float m = pe - 2.0f * truncf(pe * 0.5f);
    // revolutions; +0.25 rev == +pi/2 rad turns sin into cos. Single-rounding fma.
    const float INV_2PI = 0.15915494309189535f;
    float off = (m == 0.0f) ? 0.0f : 0.25f;
    float r = fmaf(pe, INV_2PI, off);
    float fr = r - floorf(r);          // reduce to [0,1) for v_sin_f32
    float s;
    asm("v_sin_f32 %0, %1" : "=v"(s) : "v"(fr));
    return s;
}

__global__ __launch_bounds__(256) void PositionalEmbedding_75685913690611_kernel(
    const float* __restrict__ div, float* __restrict__ out) {
    int idx = blockIdx.x * blockDim.x + threadIdx.x;  // 0 .. P*E/4-1
    int row = idx >> 8;        // / (E/4)
    int cg  = idx & 255;       // % (E/4)

    float p = (float)row;      // exact in fp32 (p < 2^15)
    float4 d = *reinterpret_cast<const float4*>(div + (cg << 2));

    float4 o;
    o.x = sincos_sel(p * d.x);
    o.y = sincos_sel(p * d.y);
    o.z = sincos_sel(p * d.z);
    o.w = sincos_sel(p * d.w);

    reinterpret_cast<float4*>(out)[idx] = o;
}

extern "C" void kernel_launch(void* const* d_in, const int* in_sizes, int n_in,
                              void* d_out, int out_size, void* d_ws, size_t ws_size,
                              hipStream_t stream) {
    const float* div = (const float*)d_in[1];  // d_in[0] = x (shape-only)
    float* out = (float*)d_out;                // out_size = 32768*1024

    int total4 = (PE_P * PE_E) / 4;            // 8,388,608 float4 stores
    int block = 256;
    int grid = total4 / block;                 // 32768 blocks
    PositionalEmbedding_75685913690611_kernel<<<grid, block, 0, stream>>>(div, out);
}

// Round 3
// 25.748 us; speedup vs baseline: 1.5124x; 1.0017x over previous
//
#include <hip/hip_runtime.h>

// PositionalEmbedding: out[p][e] = (fmod(p*div[e], 2) == 0) ? sin(p*div[e]) : cos(p*div[e])
// P = 32768 positions, E = 1024 embedding dims. Output fp32, write-only ~134 MB.
//
// HW v_sin_f32 (input in REVOLUTIONS, v_fract-reduced); cos folded via +0.25 rev.
// Parity test in exact arithmetic (== fmodf for pe < 2^24).
// Each thread: 4 rows x 4 cols = 16 elems, one div float4 reused, 4 float4 stores.

#define PE_E 1024
#define PE_P 32768

__device__ __forceinline__ float sincos_sel(float pe) {
    // exact fmod(pe, 2): all steps exact in fp32 for |pe| < 2^24
    float m = __builtin_fmaf(-2.0f, truncf(pe * 0.5f), pe);
    const float INV_2PI = 0.15915494309189535f;
    float off = (m == 0.0f) ? 0.0f : 0.25f;   // +0.25 rev == +pi/2: sin -> cos
    float r = __builtin_fmaf(pe, INV_2PI, off);
    float fr = __builtin_amdgcn_fractf(r);     // v_fract_f32: reduce to [0,1)
    return __builtin_amdgcn_sinf(fr);          // v_sin_f32 (revolutions)
}

__global__ __launch_bounds__(256) void PositionalEmbedding_75685913690611_kernel(
    const float* __restrict__ div, float* __restrict__ out) {
    // t in [0, P/4 * E/4): cg = column-group, rowBase = 4 consecutive rows
    int t = blockIdx.x * blockDim.x + threadIdx.x;
    int cg      = t & 255;          // E/4 = 256 column groups
    int rowBase = (t >> 8) << 2;    // 4 rows per thread

    float4 d = *reinterpret_cast<const float4*>(div + (cg << 2));
    float4* outv = reinterpret_cast<float4*>(out);

    #pragma unroll
    for (int i = 0; i < 4; ++i) {
        float p = (float)(rowBase + i);   // exact in fp32 (p < 2^15)
        float4 o;
        o.x = sincos_sel(p * d.x);
        o.y = sincos_sel(p * d.y);
        o.z = sincos_sel(p * d.z);
        o.w = sincos_sel(p * d.w);
        outv[(rowBase + i) * 256 + cg] = o;   // wave-coalesced (consecutive cg)
    }
}

extern "C" void kernel_launch(void* const* d_in, const int* in_sizes, int n_in,
                              void* d_out, int out_size, void* d_ws, size_t ws_size,
                              hipStream_t stream) {
    const float* div = (const float*)d_in[1];  // d_in[0] = x (shape-only)
    float* out = (float*)d_out;                // out_size = 32768*1024

    int threads_total = (PE_P / 4) * (PE_E / 4);  // 2,097,152
    int block = 256;
    int grid = threads_total / block;             // 8192 blocks
    PositionalEmbedding_75685913690611_kernel<<<grid, block, 0, stream>>>(div, out);
}